// Round 14
// baseline (62.304 us; speedup 1.0000x reference)
//
#include <hip/hip_runtime.h>
#include <hip/hip_bf16.h>
#include <cstdint>
#include <cstddef>

typedef short bf16x8 __attribute__((ext_vector_type(8)));
typedef float f32x4 __attribute__((ext_vector_type(4)));

#define BN 8
#define TN 2048
#define CN 1024
#define HN 64

__device__ __forceinline__ unsigned short f2bf(float f) {
    unsigned int u = __float_as_uint(f);
    u += 0x7fffu + ((u >> 16) & 1u);
    return (unsigned short)(u >> 16);
}

// packed f32x2 -> bf16x2 (v_cvt_pk_bf16_f32), lo in low half
__device__ __forceinline__ int pk2(float lo, float hi) {
    float2 t; t.x = lo; t.y = hi;
    __hip_bfloat162 h = __float22bfloat162_rn(t);
    return *reinterpret_cast<int*>(&h);
}

// async global->LDS copy, 16 B per lane; ldst is the WAVE-UNIFORM base
// (HW adds lane*16), gsrc is per-lane.
__device__ __forceinline__ void gload16(const void* gsrc, void* ldst) {
    __builtin_amdgcn_global_load_lds(
        (const __attribute__((address_space(1))) unsigned int*)gsrc,
        (__attribute__((address_space(3))) unsigned int*)ldst,
        16, 0, 0);
}

// Build Wp: W in MFMA-B-fragment-packed order.
// Logical Wct[n][c], n in [0,192): n<64 = Wq col h (pre-scaled by 0.125*log2e),
// 64..127 = Wk, 128..191 = Wv.  Fragment (tile=n>>4, kk=c>>5): lane = lg*16+lq
// (lg=(c>>3)&3, lq=n&15), elem e=c&7.
__global__ __launch_bounds__(256) void wconv_kernel(const float* __restrict__ Wq,
                                                    const float* __restrict__ Wk,
                                                    const float* __restrict__ Wv,
                                                    unsigned short* __restrict__ Wp) {
    int idx = blockIdx.x * 256 + threadIdx.x;   // 0..196607
    int n = idx >> 10;
    int c = idx & 1023;
    int m = n >> 6;
    int h = n & 63;
    const float* W = (m == 0) ? Wq : ((m == 1) ? Wk : Wv);
    float v = W[c * 64 + h];
    if (m == 0) v *= 0.18033688011112042f;  // (1/sqrt(64)) * log2(e)
    const int tile = n >> 4, lq = n & 15;
    const int kk = c >> 5, lg = (c >> 3) & 3, e = c & 7;
    Wp[(size_t)(((tile * 32 + kk) * 64 + lg * 16 + lq) * 8 + e)] = f2bf(v);
}

// Fused QKV projection v13: WAVE-PRIVATE, ZERO-BARRIER pipeline.
// 512 blocks x 64 threads (1 wave).  Wave = 32 rows x ALL 192 cols
// (24 f32x4 accumulators).  BK=32 -> 32 K-steps.
// Per step, the wave DMAs its own fragments via global_load_lds into a
// private 3-slot LDS ring (16 KB/slot: X fp32 4 KB + W bf16 12 KB):
//   X call (m,h): lane l <- X[rowbase+m*16+(l&15)][s*32+(l>>4)*8+h*4 ..+4)
//   W call j:     lane l <- Wp fragment (tile j, kk=s), lane l's 16 B
// Store mapping == fragment mapping, so read-back is identity l*16
// (conflict-free, no redistribution).  Counted s_waitcnt vmcnt(32) keeps
// slots s+1, s+2 (32 loads) in flight; NO s_barrier / __syncthreads at all.
// Slot-reuse safety: ring depth 3 with stage-ahead 2 + in-order issue.
__global__ __launch_bounds__(64) void proj_kernel(const float* __restrict__ X,
                                                  const unsigned short* __restrict__ Wp,
                                                  unsigned short* __restrict__ Qs,
                                                  unsigned short* __restrict__ Kp,
                                                  unsigned short* __restrict__ Vp) {
    __shared__ __align__(16) char ring[3][16384];   // 48 KB, wave-private

    const int l  = threadIdx.x;
    const int lq = l & 15;
    const int lg = l >> 4;
    const int rowbase = blockIdx.x * 32;

    // global base pointers (step s adds s*32 floats for X, s*512 elems for W)
    const float* xs[2][2];
    #pragma unroll
    for (int m = 0; m < 2; ++m)
        #pragma unroll
        for (int h = 0; h < 2; ++h)
            xs[m][h] = X + (size_t)(rowbase + m * 16 + lq) * CN + lg * 8 + h * 4;
    const unsigned short* wsrc[12];
    #pragma unroll
    for (int j = 0; j < 12; ++j)
        wsrc[j] = Wp + (size_t)(j * 32) * 512 + l * 8;

    const f32x4 zero4 = {0.f, 0.f, 0.f, 0.f};
    f32x4 acc0[12], acc1[12];
    #pragma unroll
    for (int j = 0; j < 12; ++j) { acc0[j] = zero4; acc1[j] = zero4; }

    // STAGE(s, slot): 16 async 1-KB copies, wave-private dst
    #define STAGE(s, slot)                                                  \
        {                                                                   \
            char* base_ = ring[slot];                                       \
            gload16(xs[0][0] + (s) * 32, base_ + 0 * 1024);                 \
            gload16(xs[0][1] + (s) * 32, base_ + 1 * 1024);                 \
            gload16(xs[1][0] + (s) * 32, base_ + 2 * 1024);                 \
            gload16(xs[1][1] + (s) * 32, base_ + 3 * 1024);                 \
            _Pragma("unroll")                                               \
            for (int j_ = 0; j_ < 12; ++j_)                                 \
                gload16(wsrc[j_] + (s) * 512, base_ + 4096 + j_ * 1024);    \
        }

    // prologue: steps 0,1 -> slots 0,1 (32 loads outstanding)
    STAGE(0, 0)
    STAGE(1, 1)

    int rc = 0;   // slot holding step s
    int rp = 2;   // slot to stage step s+2 into
    for (int s = 0; s < 32; ++s) {
        if (s <= 29) {
            STAGE(s + 2, rp)
            asm volatile("s_waitcnt vmcnt(32)" ::: "memory");  // slot s done
        } else if (s == 30) {
            asm volatile("s_waitcnt vmcnt(16)" ::: "memory");
        } else {
            asm volatile("s_waitcnt vmcnt(0)" ::: "memory");
        }
        __builtin_amdgcn_sched_barrier(0);
        const char* base = ring[rc];
        // A-fragments: identity read-back (lane's own 16 B pieces), cvt to bf16
        bf16x8 a0, a1;
        {
            float4 xa = *(const float4*)(base + 0 * 1024 + l * 16);
            float4 xb = *(const float4*)(base + 1 * 1024 + l * 16);
            union { bf16x8 v; int u[4]; } ua;
            ua.u[0] = pk2(xa.x, xa.y); ua.u[1] = pk2(xa.z, xa.w);
            ua.u[2] = pk2(xb.x, xb.y); ua.u[3] = pk2(xb.z, xb.w);
            a0 = ua.v;
            float4 xc = *(const float4*)(base + 2 * 1024 + l * 16);
            float4 xd = *(const float4*)(base + 3 * 1024 + l * 16);
            union { bf16x8 v; int u[4]; } ub;
            ub.u[0] = pk2(xc.x, xc.y); ub.u[1] = pk2(xc.z, xc.w);
            ub.u[2] = pk2(xd.x, xd.y); ub.u[3] = pk2(xd.z, xd.w);
            a1 = ub.v;
        }
        #pragma unroll
        for (int j = 0; j < 12; ++j) {
            bf16x8 b = *(const bf16x8*)(base + 4096 + j * 1024 + l * 16);
            acc0[j] = __builtin_amdgcn_mfma_f32_16x16x32_bf16(a0, b, acc0[j], 0, 0, 0);
            acc1[j] = __builtin_amdgcn_mfma_f32_16x16x32_bf16(a1, b, acc1[j], 0, 0, 0);
        }
        rc = (rc == 2) ? 0 : rc + 1;
        rp = (rp == 2) ? 0 : rp + 1;
    }
    #undef STAGE

    // D layout: col = lane&15 (W col), row = 4*(lane>>4) + reg (X row)
    #pragma unroll
    for (int m = 0; m < 2; ++m) {
        #pragma unroll
        for (int j = 0; j < 12; ++j) {
            const int col = j * 16 + lq;
            const int mtx = col >> 6;          // 0=Q, 1=K, 2=V
            const int h   = col & 63;
            #pragma unroll
            for (int i = 0; i < 4; ++i) {
                const int g = rowbase + m * 16 + 4 * lg + i;   // global token row
                const float av = (m == 0) ? acc0[j][i] : acc1[j][i];
                const unsigned short val = f2bf(av);
                const int b = g >> 11, tloc = g & 2047;
                const int kt = tloc >> 5;
                if (mtx == 0) {
                    Qs[(size_t)g * 64 + h] = val;
                } else if (mtx == 1) {
                    // K fragment-packed: frag = fa*2+ks, lane = lgk*16+lqk, elem e
                    const int fa = (tloc >> 4) & 1, lqk = tloc & 15;
                    const int ks = h >> 5, lgk = (h >> 3) & 3, e = h & 7;
                    Kp[(size_t)(b * 64 + kt) * 2048 + (fa * 2 + ks) * 512 +
                       (lgk * 16 + lqk) * 8 + e] = val;
                } else {
                    // V fragment-packed: frag = nf, lane = lgv*16+lqv, elem e
                    const int tt = tloc & 31;
                    const int lgv = (tt & 15) >> 2;
                    const int e = (tt < 16) ? (tt & 3) : 4 + (tt & 3);
                    const int nf = h >> 4, lqv = h & 15;
                    Vp[(size_t)(b * 64 + kt) * 2048 + nf * 512 +
                       (lgv * 16 + lqv) * 8 + e] = val;
                }
            }
        }
    }
}

// Block-cooperative causal flash attention, fragment-packed K/V.
// Block = (qt, b): 1024 blocks x 4 waves; heavy q-tiles launch first.
// Waves split the q-tile's key-tiles round-robin; partials merged in LDS.
// S^T = mfma(K, Q): lane&15 = query, key = 16*fa + 4*(lane>>4) + reg.
__global__ __launch_bounds__(256) void attn_kernel(const unsigned short* __restrict__ Qs,
                                                   const unsigned short* __restrict__ Kp,
                                                   const unsigned short* __restrict__ Vp,
                                                   float* __restrict__ Out) {
    __shared__ float lm[4][16];
    __shared__ float ll[4][16];
    __shared__ float facc[4][1024];

    const int tid = threadIdx.x;
    const int w  = tid >> 6;
    const int l  = tid & 63;
    const int lq = l & 15;
    const int lg = l >> 4;
    const int bid = blockIdx.x;
    const int qt = 127 - (bid >> 3);   // heavy first
    const int b  = bid & 7;
    const int q0 = qt * 16;
    const int nt = (qt >> 1) + 1;

    const unsigned short* Qb = Qs + (size_t)b * TN * 64;
    const unsigned short* KVbase_k = Kp + (size_t)b * 64 * 2048 + (size_t)l * 8;
    const unsigned short* KVbase_v = Vp + (size_t)b * 64 * 2048 + (size_t)l * 8;

    const f32x4 zero4 = {0.f, 0.f, 0.f, 0.f};

    bf16x8 qa0 = *(const bf16x8*)(Qb + (size_t)(q0 + lq) * 64 + lg * 8);
    bf16x8 qa1 = *(const bf16x8*)(Qb + (size_t)(q0 + lq) * 64 + 32 + lg * 8);

    f32x4 acc[4] = {zero4, zero4, zero4, zero4};
    float mrow = -1e30f;
    float lrow = 0.f;

    bf16x8 Kc[4], Vc[4], Kn[4], Vn[4];
    int kt = w;
    if (kt < nt) {
        const size_t tb = (size_t)kt * 2048;
        #pragma unroll
        for (int i = 0; i < 4; ++i) {
            Kc[i] = *(const bf16x8*)(KVbase_k + tb + i * 512);
            Vc[i] = *(const bf16x8*)(KVbase_v + tb + i * 512);
        }
    }

    for (; kt < nt; kt += 4) {
        const int ktn = kt + 4;
        if (ktn < nt) {   // prefetch next tile (coalesced 1KB loads)
            const size_t tb = (size_t)ktn * 2048;
            #pragma unroll
            for (int i = 0; i < 4; ++i) {
                Kn[i] = *(const bf16x8*)(KVbase_k + tb + i * 512);
                Vn[i] = *(const bf16x8*)(KVbase_v + tb + i * 512);
            }
        }

        const int key0 = kt * 32;
        f32x4 s[2];
        s[0] = __builtin_amdgcn_mfma_f32_16x16x32_bf16(Kc[0], qa0, zero4, 0, 0, 0);
        s[0] = __builtin_amdgcn_mfma_f32_16x16x32_bf16(Kc[1], qa1, s[0], 0, 0, 0);
        s[1] = __builtin_amdgcn_mfma_f32_16x16x32_bf16(Kc[2], qa0, zero4, 0, 0, 0);
        s[1] = __builtin_amdgcn_mfma_f32_16x16x32_bf16(Kc[3], qa1, s[1], 0, 0, 0);

        if (kt == nt - 1) {   // only the diagonal tile needs masking
            const int q = q0 + lq;
            #pragma unroll
            for (int fa = 0; fa < 2; ++fa)
                #pragma unroll
                for (int r = 0; r < 4; ++r) {
                    const int key = key0 + fa * 16 + 4 * lg + r;
                    if (key > q) s[fa][r] = -1e30f;
                }
        }

        float m1 = fmaxf(fmaxf(s[0][0], s[0][1]), s[0][2]);
        float m2 = fmaxf(fmaxf(s[0][3], s[1][0]), s[1][1]);
        float m3 = fmaxf(fmaxf(s[1][2], s[1][3]), m1);
        float tm = fmaxf(m2, m3);
        tm = fmaxf(tm, __shfl_xor(tm, 16));
        tm = fmaxf(tm, __shfl_xor(tm, 32));

        // defer-max: only rescale when max grows by > 8 (P bounded by 2^8)
        if (!__all(tm <= mrow + 8.0f)) {
            const float mnew = fmaxf(mrow, tm);
            const float cc = __builtin_amdgcn_exp2f(mrow - mnew);
            lrow *= cc;
            float cb[4];
            #pragma unroll
            for (int i = 0; i < 4; ++i) cb[i] = __shfl(cc, 4 * lg + i);
            #pragma unroll
            for (int nf = 0; nf < 4; ++nf)
                #pragma unroll
                for (int i = 0; i < 4; ++i) acc[nf][i] *= cb[i];
            mrow = mnew;
        }

        float p[2][4];
        float psum = 0.f;
        #pragma unroll
        for (int fa = 0; fa < 2; ++fa)
            #pragma unroll
            for (int r = 0; r < 4; ++r) {
                p[fa][r] = __builtin_amdgcn_exp2f(s[fa][r] - mrow);
                psum += p[fa][r];
            }
        psum += __shfl_xor(psum, 16);
        psum += __shfl_xor(psum, 32);
        lrow += psum;

        bf16x8 pa;
        pa[0] = (short)f2bf(p[0][0]); pa[1] = (short)f2bf(p[0][1]);
        pa[2] = (short)f2bf(p[0][2]); pa[3] = (short)f2bf(p[0][3]);
        pa[4] = (short)f2bf(p[1][0]); pa[5] = (short)f2bf(p[1][1]);
        pa[6] = (short)f2bf(p[1][2]); pa[7] = (short)f2bf(p[1][3]);

        acc[0] = __builtin_amdgcn_mfma_f32_16x16x32_bf16(pa, Vc[0], acc[0], 0, 0, 0);
        acc[1] = __builtin_amdgcn_mfma_f32_16x16x32_bf16(pa, Vc[1], acc[1], 0, 0, 0);
        acc[2] = __builtin_amdgcn_mfma_f32_16x16x32_bf16(pa, Vc[2], acc[2], 0, 0, 0);
        acc[3] = __builtin_amdgcn_mfma_f32_16x16x32_bf16(pa, Vc[3], acc[3], 0, 0, 0);

        #pragma unroll
        for (int i = 0; i < 4; ++i) { Kc[i] = Kn[i]; Vc[i] = Vn[i]; }
    }

    // store partial state to LDS
    if (lg == 0) {
        lm[w][lq] = mrow;
        ll[w][lq] = lrow;
    }
    #pragma unroll
    for (int nf = 0; nf < 4; ++nf)
        #pragma unroll
        for (int i = 0; i < 4; ++i)
            facc[w][(4 * lg + i) * 64 + nf * 16 + lq] = acc[nf][i];

    __syncthreads();

    // merge 4 wave-partials and write Out
    #pragma unroll
    for (int ii = 0; ii < 4; ++ii) {
        const int e = tid + ii * 256;
        const int q = e >> 6;
        const int h = e & 63;
        const float M = fmaxf(fmaxf(lm[0][q], lm[1][q]),
                              fmaxf(lm[2][q], lm[3][q]));
        float L = 0.f, O = 0.f;
        #pragma unroll
        for (int c = 0; c < 4; ++c) {
            const float wgt = __builtin_amdgcn_exp2f(lm[c][q] - M);
            L += wgt * ll[c][q];
            O += wgt * facc[c][q * 64 + h];
        }
        Out[((size_t)b * TN + q0 + q) * 64 + h] = O / L;
    }
}

extern "C" void kernel_launch(void* const* d_in, const int* in_sizes, int n_in,
                              void* d_out, int out_size, void* d_ws, size_t ws_size,
                              hipStream_t stream) {
    const float* X  = (const float*)d_in[0];
    const float* Wq = (const float*)d_in[1];
    const float* Wk = (const float*)d_in[2];
    const float* Wv = (const float*)d_in[3];
    float* Out = (float*)d_out;

    char* ws = (char*)d_ws;
    unsigned short* Wp = (unsigned short*)(ws);                 // 384 KB (pad 512 KB)
    unsigned short* Qs = (unsigned short*)(ws + (512u << 10));  // 2 MB
    unsigned short* Kp = Qs + (size_t)16384 * 64;               // 2 MB
    unsigned short* Vp = Kp + (size_t)16384 * 64;               // 2 MB

    hipLaunchKernelGGL(wconv_kernel, dim3(768), dim3(256), 0, stream, Wq, Wk, Wv, Wp);
    hipLaunchKernelGGL(proj_kernel,  dim3(512), dim3(64), 0, stream, X, Wp, Qs, Kp, Vp);
    hipLaunchKernelGGL(attn_kernel,  dim3(1024), dim3(256), 0, stream, Qs, Kp, Vp, Out);
}

// Round 16
// 46.801 us; speedup vs baseline: 1.3313x; 1.3313x over previous
//
#include <hip/hip_runtime.h>
#include <hip/hip_bf16.h>
#include <cstdint>
#include <cstddef>

typedef short bf16x8 __attribute__((ext_vector_type(8)));
typedef float f32x4 __attribute__((ext_vector_type(4)));

#define BN 8
#define TN 2048
#define CN 1024
#define HN 64

__device__ __forceinline__ unsigned short f2bf(float f) {
    unsigned int u = __float_as_uint(f);
    u += 0x7fffu + ((u >> 16) & 1u);
    return (unsigned short)(u >> 16);
}

// packed f32x2 -> bf16x2 (v_cvt_pk_bf16_f32), lo in low half
__device__ __forceinline__ int pk2(float lo, float hi) {
    float2 t; t.x = lo; t.y = hi;
    __hip_bfloat162 h = __float22bfloat162_rn(t);
    return *reinterpret_cast<int*>(&h);
}

// async global->LDS copy, 16 B per lane; ldst must be the WAVE-UNIFORM base
// (HW adds lane*16), gsrc is per-lane.
__device__ __forceinline__ void gload_lds16(const unsigned short* gsrc, void* ldst) {
    __builtin_amdgcn_global_load_lds(
        (const __attribute__((address_space(1))) unsigned int*)gsrc,
        (__attribute__((address_space(3))) unsigned int*)ldst,
        16, 0, 0);
}

// Build Wp: W in MFMA-B-fragment-packed order.  (round-8 proven, verbatim)
__global__ __launch_bounds__(256) void wconv_kernel(const float* __restrict__ Wq,
                                                    const float* __restrict__ Wk,
                                                    const float* __restrict__ Wv,
                                                    unsigned short* __restrict__ Wp) {
    int idx = blockIdx.x * 256 + threadIdx.x;   // 0..196607
    int n = idx >> 10;
    int c = idx & 1023;
    int m = n >> 6;
    int h = n & 63;
    const float* W = (m == 0) ? Wq : ((m == 1) ? Wk : Wv);
    float v = W[c * 64 + h];
    if (m == 0) v *= 0.18033688011112042f;  // (1/sqrt(64)) * log2(e)
    const int tile = n >> 4, lq = n & 15;
    const int kk = c >> 5, lg = (c >> 3) & 3, e = c & 7;
    Wp[(size_t)(((tile * 32 + kk) * 64 + lg * 16 + lq) * 8 + e)] = f2bf(v);
}

// Fused QKV projection (round-8 v8, proven, verbatim): m97-style dbuf LDS,
// W staged async via global_load_lds, X reg-staged + packed cvt.
// 512 blocks x 512 threads (8 waves).  BM=32, BN=192, BK=64, 16 K-steps.
__global__ __launch_bounds__(512) void proj_kernel(const float* __restrict__ X,
                                                   const unsigned short* __restrict__ Wp,
                                                   unsigned short* __restrict__ Qs,
                                                   unsigned short* __restrict__ Kp,
                                                   unsigned short* __restrict__ Vp) {
    __shared__ short Xs[2][32 * 64];      // 2 x 4 KB bf16
    __shared__ short Wsh[2][12288];       // 2 x 24 KB bf16

    const int tid = threadIdx.x;
    const int w   = tid >> 6;       // 0..7
    const int l   = tid & 63;
    const int lq  = l & 15;
    const int lg  = l >> 4;
    const int wr  = w >> 2;         // M-half
    const int wc  = w & 3;          // N-quarter
    const int rowbase = blockIdx.x * 32;

    const int xrow = tid >> 4;             // 0..31
    const float* xsrc = X + (size_t)(rowbase + xrow) * CN + (tid & 15) * 4;
    const int xdst = xrow * 128 + (((tid & 15) * 8) ^ ((xrow & 7) << 4));  // byte

    const unsigned short* wsrc[3];
    int wbase[3];                          // wave-uniform LDS elem offset
    #pragma unroll
    for (int j = 0; j < 3; ++j) {
        const int el  = j * 4096 + tid * 8;
        const int blk = el >> 9;
        const int t   = blk >> 1, kkL = blk & 1;
        wsrc[j]  = Wp + (t * 32 + kkL) * 512 + (el & 511);
        wbase[j] = j * 4096 + w * 512;
    }

    const int arow = wr * 16 + lq;
    int aaddr[2];
    #pragma unroll
    for (int kkL = 0; kkL < 2; ++kkL)
        aaddr[kkL] = arow * 128 + (((kkL * 64 + lg * 16)) ^ ((arow & 7) << 4));
    int baddr[2][3];
    #pragma unroll
    for (int kkL = 0; kkL < 2; ++kkL)
        #pragma unroll
        for (int jj = 0; jj < 3; ++jj)
            baddr[kkL][jj] = (((wc * 3 + jj) * 2 + kkL) * 64 + l) * 16;  // byte

    const f32x4 zero4 = {0.f, 0.f, 0.f, 0.f};
    f32x4 acc[3] = {zero4, zero4, zero4};

    {
        #pragma unroll
        for (int j = 0; j < 3; ++j)
            gload_lds16(wsrc[j], (char*)Wsh[0] + wbase[j] * 2);
        float4 xr = *(const float4*)(xsrc);
        int2 xc; xc.x = pk2(xr.x, xr.y); xc.y = pk2(xr.z, xr.w);
        *(int2*)((char*)Xs[0] + xdst) = xc;
        __syncthreads();
    }

    for (int s = 0; s < 16; ++s) {
        const int cur = s & 1;
        const int nxt = cur ^ 1;
        const bool more = (s + 1) < 16;
        float4 xr;
        if (more) {
            #pragma unroll
            for (int j = 0; j < 3; ++j)
                gload_lds16(wsrc[j] + (s + 1) * 1024, (char*)Wsh[nxt] + wbase[j] * 2);
            xr = *(const float4*)(xsrc + (s + 1) * 64);
        }
        #pragma unroll
        for (int kkL = 0; kkL < 2; ++kkL) {
            bf16x8 a  = *(const bf16x8*)((char*)Xs[cur] + aaddr[kkL]);
            bf16x8 b0 = *(const bf16x8*)((char*)Wsh[cur] + baddr[kkL][0]);
            bf16x8 b1 = *(const bf16x8*)((char*)Wsh[cur] + baddr[kkL][1]);
            bf16x8 b2 = *(const bf16x8*)((char*)Wsh[cur] + baddr[kkL][2]);
            acc[0] = __builtin_amdgcn_mfma_f32_16x16x32_bf16(a, b0, acc[0], 0, 0, 0);
            acc[1] = __builtin_amdgcn_mfma_f32_16x16x32_bf16(a, b1, acc[1], 0, 0, 0);
            acc[2] = __builtin_amdgcn_mfma_f32_16x16x32_bf16(a, b2, acc[2], 0, 0, 0);
        }
        if (more) {
            int2 xc; xc.x = pk2(xr.x, xr.y); xc.y = pk2(xr.z, xr.w);
            *(int2*)((char*)Xs[nxt] + xdst) = xc;
        }
        __syncthreads();
    }

    #pragma unroll
    for (int j = 0; j < 3; ++j) {
        const int col = wc * 48 + j * 16 + lq;
        const int mtx = col >> 6;          // 0=Q, 1=K, 2=V
        const int h   = col & 63;
        #pragma unroll
        for (int i = 0; i < 4; ++i) {
            const int g = rowbase + wr * 16 + 4 * lg + i;
            const unsigned short val = f2bf(acc[j][i]);
            const int b = g >> 11, tloc = g & 2047;
            const int kt = tloc >> 5;
            if (mtx == 0) {
                Qs[(size_t)g * 64 + h] = val;
            } else if (mtx == 1) {
                const int fa = (tloc >> 4) & 1, lqk = tloc & 15;
                const int ks = h >> 5, lgk = (h >> 3) & 3, e = h & 7;
                Kp[(size_t)(b * 64 + kt) * 2048 + (fa * 2 + ks) * 512 +
                   (lgk * 16 + lqk) * 8 + e] = val;
            } else {
                const int tt = tloc & 31;
                const int lgv = (tt & 15) >> 2;
                const int e = (tt < 16) ? (tt & 3) : 4 + (tt & 3);
                const int nf = h >> 4, lqv = h & 15;
                Vp[(size_t)(b * 64 + kt) * 2048 + nf * 512 +
                   (lgv * 16 + lqv) * 8 + e] = val;
            }
        }
    }
}

// Paired-q-tile causal flash attention: block = (pair a, batch b), 512 blocks
// x 4 waves.  q-tiles 2a and 2a+1 share the SAME key-tile range (nt = a+1),
// so each K/V tile is loaded ONCE and applied to both (2x QK^T, 2x softmax
// state, 2x PV) -> K/V + Q fetch traffic halves vs round-8.
// Inner math byte-identical to the proven round-8 body.
__global__ __launch_bounds__(256) void attn_kernel(const unsigned short* __restrict__ Qs,
                                                   const unsigned short* __restrict__ Kp,
                                                   const unsigned short* __restrict__ Vp,
                                                   float* __restrict__ Out) {
    __shared__ float lm[2][4][16];
    __shared__ float ll[2][4][16];
    __shared__ float facc[2][4][1024];

    const int tid = threadIdx.x;
    const int w  = tid >> 6;
    const int l  = tid & 63;
    const int lq = l & 15;
    const int lg = l >> 4;
    const int bid = blockIdx.x;
    const int a  = 63 - (bid >> 3);   // heavy pairs first
    const int b  = bid & 7;
    const int nt = a + 1;
    const int q00 = 32 * a;           // qt0 = 2a
    const int q01 = 32 * a + 16;      // qt1 = 2a+1

    const unsigned short* Qb = Qs + (size_t)b * TN * 64;
    const unsigned short* KVbase_k = Kp + (size_t)b * 64 * 2048 + (size_t)l * 8;
    const unsigned short* KVbase_v = Vp + (size_t)b * 64 * 2048 + (size_t)l * 8;

    const f32x4 zero4 = {0.f, 0.f, 0.f, 0.f};

    bf16x8 qa00 = *(const bf16x8*)(Qb + (size_t)(q00 + lq) * 64 + lg * 8);
    bf16x8 qa10 = *(const bf16x8*)(Qb + (size_t)(q00 + lq) * 64 + 32 + lg * 8);
    bf16x8 qa01 = *(const bf16x8*)(Qb + (size_t)(q01 + lq) * 64 + lg * 8);
    bf16x8 qa11 = *(const bf16x8*)(Qb + (size_t)(q01 + lq) * 64 + 32 + lg * 8);

    f32x4 acc0[4] = {zero4, zero4, zero4, zero4};
    f32x4 acc1[4] = {zero4, zero4, zero4, zero4};
    float mrow0 = -1e30f, lrow0 = 0.f;
    float mrow1 = -1e30f, lrow1 = 0.f;

    bf16x8 Kc[4], Vc[4], Kn[4], Vn[4];
    int kt = w;
    if (kt < nt) {
        const size_t tb = (size_t)kt * 2048;
        #pragma unroll
        for (int i = 0; i < 4; ++i) {
            Kc[i] = *(const bf16x8*)(KVbase_k + tb + i * 512);
            Vc[i] = *(const bf16x8*)(KVbase_v + tb + i * 512);
        }
    }

    // softmax + PV for one q-tile's state (round-8 body, verbatim math)
    #define SOFTMAX_PV(S, MROW, LROW, ACC)                                        \
        do {                                                                      \
            float m1 = fmaxf(fmaxf(S[0][0], S[0][1]), S[0][2]);                   \
            float m2 = fmaxf(fmaxf(S[0][3], S[1][0]), S[1][1]);                   \
            float m3 = fmaxf(fmaxf(S[1][2], S[1][3]), m1);                        \
            float tm = fmaxf(m2, m3);                                             \
            tm = fmaxf(tm, __shfl_xor(tm, 16));                                   \
            tm = fmaxf(tm, __shfl_xor(tm, 32));                                   \
            if (!__all(tm <= MROW + 8.0f)) {                                      \
                const float mnew = fmaxf(MROW, tm);                               \
                const float cc = __builtin_amdgcn_exp2f(MROW - mnew);             \
                LROW *= cc;                                                       \
                float cb[4];                                                      \
                _Pragma("unroll")                                                 \
                for (int i = 0; i < 4; ++i) cb[i] = __shfl(cc, 4 * lg + i);       \
                _Pragma("unroll")                                                 \
                for (int nf = 0; nf < 4; ++nf)                                    \
                    _Pragma("unroll")                                             \
                    for (int i = 0; i < 4; ++i) ACC[nf][i] *= cb[i];              \
                MROW = mnew;                                                      \
            }                                                                     \
            float p[2][4];                                                        \
            float psum = 0.f;                                                     \
            _Pragma("unroll")                                                     \
            for (int fa = 0; fa < 2; ++fa)                                        \
                _Pragma("unroll")                                                 \
                for (int r = 0; r < 4; ++r) {                                     \
                    p[fa][r] = __builtin_amdgcn_exp2f(S[fa][r] - MROW);           \
                    psum += p[fa][r];                                             \
                }                                                                 \
            psum += __shfl_xor(psum, 16);                                         \
            psum += __shfl_xor(psum, 32);                                         \
            LROW += psum;                                                         \
            bf16x8 pa;                                                            \
            pa[0] = (short)f2bf(p[0][0]); pa[1] = (short)f2bf(p[0][1]);           \
            pa[2] = (short)f2bf(p[0][2]); pa[3] = (short)f2bf(p[0][3]);           \
            pa[4] = (short)f2bf(p[1][0]); pa[5] = (short)f2bf(p[1][1]);           \
            pa[6] = (short)f2bf(p[1][2]); pa[7] = (short)f2bf(p[1][3]);           \
            ACC[0] = __builtin_amdgcn_mfma_f32_16x16x32_bf16(pa, Vc[0], ACC[0], 0, 0, 0); \
            ACC[1] = __builtin_amdgcn_mfma_f32_16x16x32_bf16(pa, Vc[1], ACC[1], 0, 0, 0); \
            ACC[2] = __builtin_amdgcn_mfma_f32_16x16x32_bf16(pa, Vc[2], ACC[2], 0, 0, 0); \
            ACC[3] = __builtin_amdgcn_mfma_f32_16x16x32_bf16(pa, Vc[3], ACC[3], 0, 0, 0); \
        } while (0)

    for (; kt < nt; kt += 4) {
        const int ktn = kt + 4;
        if (ktn < nt) {   // prefetch next tile (coalesced 1KB loads)
            const size_t tb = (size_t)ktn * 2048;
            #pragma unroll
            for (int i = 0; i < 4; ++i) {
                Kn[i] = *(const bf16x8*)(KVbase_k + tb + i * 512);
                Vn[i] = *(const bf16x8*)(KVbase_v + tb + i * 512);
            }
        }

        const int key0 = kt * 32;
        f32x4 s0[2], s1[2];
        s0[0] = __builtin_amdgcn_mfma_f32_16x16x32_bf16(Kc[0], qa00, zero4, 0, 0, 0);
        s0[0] = __builtin_amdgcn_mfma_f32_16x16x32_bf16(Kc[1], qa10, s0[0], 0, 0, 0);
        s0[1] = __builtin_amdgcn_mfma_f32_16x16x32_bf16(Kc[2], qa00, zero4, 0, 0, 0);
        s0[1] = __builtin_amdgcn_mfma_f32_16x16x32_bf16(Kc[3], qa10, s0[1], 0, 0, 0);
        s1[0] = __builtin_amdgcn_mfma_f32_16x16x32_bf16(Kc[0], qa01, zero4, 0, 0, 0);
        s1[0] = __builtin_amdgcn_mfma_f32_16x16x32_bf16(Kc[1], qa11, s1[0], 0, 0, 0);
        s1[1] = __builtin_amdgcn_mfma_f32_16x16x32_bf16(Kc[2], qa01, zero4, 0, 0, 0);
        s1[1] = __builtin_amdgcn_mfma_f32_16x16x32_bf16(Kc[3], qa11, s1[1], 0, 0, 0);

        if (kt == nt - 1) {   // shared diagonal tile: mask both q-tiles
            const int qg0 = q00 + lq;
            const int qg1 = q01 + lq;
            #pragma unroll
            for (int fa = 0; fa < 2; ++fa)
                #pragma unroll
                for (int r = 0; r < 4; ++r) {
                    const int key = key0 + fa * 16 + 4 * lg + r;
                    if (key > qg0) s0[fa][r] = -1e30f;
                    if (key > qg1) s1[fa][r] = -1e30f;
                }
        }

        SOFTMAX_PV(s0, mrow0, lrow0, acc0);
        SOFTMAX_PV(s1, mrow1, lrow1, acc1);

        #pragma unroll
        for (int i = 0; i < 4; ++i) { Kc[i] = Kn[i]; Vc[i] = Vn[i]; }
    }
    #undef SOFTMAX_PV

    // store partial state to LDS (hh = q-tile half)
    if (lg == 0) {
        lm[0][w][lq] = mrow0;  ll[0][w][lq] = lrow0;
        lm[1][w][lq] = mrow1;  ll[1][w][lq] = lrow1;
    }
    #pragma unroll
    for (int nf = 0; nf < 4; ++nf)
        #pragma unroll
        for (int i = 0; i < 4; ++i) {
            facc[0][w][(4 * lg + i) * 64 + nf * 16 + lq] = acc0[nf][i];
            facc[1][w][(4 * lg + i) * 64 + nf * 16 + lq] = acc1[nf][i];
        }

    __syncthreads();

    // merge 4 wave-partials per q-tile and write Out
    #pragma unroll
    for (int hh = 0; hh < 2; ++hh) {
        const int q0 = (hh == 0) ? q00 : q01;
        #pragma unroll
        for (int ii = 0; ii < 4; ++ii) {
            const int e = tid + ii * 256;
            const int q = e >> 6;
            const int h = e & 63;
            const float M = fmaxf(fmaxf(lm[hh][0][q], lm[hh][1][q]),
                                  fmaxf(lm[hh][2][q], lm[hh][3][q]));
            float L = 0.f, O = 0.f;
            #pragma unroll
            for (int c = 0; c < 4; ++c) {
                const float wgt = __builtin_amdgcn_exp2f(lm[hh][c][q] - M);
                L += wgt * ll[hh][c][q];
                O += wgt * facc[hh][c][q * 64 + h];
            }
            Out[((size_t)b * TN + q0 + q) * 64 + h] = O / L;
        }
    }
}

extern "C" void kernel_launch(void* const* d_in, const int* in_sizes, int n_in,
                              void* d_out, int out_size, void* d_ws, size_t ws_size,
                              hipStream_t stream) {
    const float* X  = (const float*)d_in[0];
    const float* Wq = (const float*)d_in[1];
    const float* Wk = (const float*)d_in[2];
    const float* Wv = (const float*)d_in[3];
    float* Out = (float*)d_out;

    char* ws = (char*)d_ws;
    unsigned short* Wp = (unsigned short*)(ws);                 // 384 KB (pad 512 KB)
    unsigned short* Qs = (unsigned short*)(ws + (512u << 10));  // 2 MB
    unsigned short* Kp = Qs + (size_t)16384 * 64;               // 2 MB
    unsigned short* Vp = Kp + (size_t)16384 * 64;               // 2 MB

    hipLaunchKernelGGL(wconv_kernel, dim3(768), dim3(256), 0, stream, Wq, Wk, Wv, Wp);
    hipLaunchKernelGGL(proj_kernel,  dim3(512), dim3(512), 0, stream, X, Wp, Qs, Kp, Vp);
    hipLaunchKernelGGL(attn_kernel,  dim3(512), dim3(256), 0, stream, Qs, Kp, Vp, Out);
}

// Round 17
// 43.382 us; speedup vs baseline: 1.4362x; 1.0788x over previous
//
#include <hip/hip_runtime.h>
#include <hip/hip_bf16.h>
#include <cstdint>
#include <cstddef>

typedef short bf16x8 __attribute__((ext_vector_type(8)));
typedef float f32x4 __attribute__((ext_vector_type(4)));
typedef float f32x16 __attribute__((ext_vector_type(16)));

#define BN 8
#define TN 2048
#define CN 1024
#define HN 64

__device__ __forceinline__ unsigned short f2bf(float f) {
    unsigned int u = __float_as_uint(f);
    u += 0x7fffu + ((u >> 16) & 1u);
    return (unsigned short)(u >> 16);
}

// packed f32x2 -> bf16x2 (v_cvt_pk_bf16_f32), lo in low half
__device__ __forceinline__ int pk2(float lo, float hi) {
    float2 t; t.x = lo; t.y = hi;
    __hip_bfloat162 h = __float22bfloat162_rn(t);
    return *reinterpret_cast<int*>(&h);
}

// async global->LDS copy, 16 B per lane; ldst must be the WAVE-UNIFORM base
// (HW adds lane*16), gsrc is per-lane.
__device__ __forceinline__ void gload_lds16(const unsigned short* gsrc, void* ldst) {
    __builtin_amdgcn_global_load_lds(
        (const __attribute__((address_space(1))) unsigned int*)gsrc,
        (__attribute__((address_space(3))) unsigned int*)ldst,
        16, 0, 0);
}

// Build Wp: W packed as 32x32x16 MFMA B-fragments.
// Logical Wct[n][c], n in [0,192): n<64 = Wq col h (pre-scaled by 0.125*log2e),
// 64..127 = Wk, 128..191 = Wv.  B-fragment (tile tc=n>>5, kk16=c>>4):
// lane l = (n&31) + 32*((c>>3)&1), elem e = c&7.
// idx = ((tc*64 + kk16)*64 + l)*8 + e  -> 1 KB lane-contiguous fragments.
__global__ __launch_bounds__(256) void wconv_kernel(const float* __restrict__ Wq,
                                                    const float* __restrict__ Wk,
                                                    const float* __restrict__ Wv,
                                                    unsigned short* __restrict__ Wp) {
    int idx = blockIdx.x * 256 + threadIdx.x;   // 0..196607
    int n = idx >> 10;
    int c = idx & 1023;
    int m = n >> 6;
    int h = n & 63;
    const float* W = (m == 0) ? Wq : ((m == 1) ? Wk : Wv);
    float v = W[c * 64 + h];
    if (m == 0) v *= 0.18033688011112042f;  // (1/sqrt(64)) * log2(e)
    const int tc = n >> 5, col = n & 31;
    const int kk16 = c >> 4, khalf = (c >> 3) & 1, e = c & 7;
    const int l = col + 32 * khalf;
    Wp[(size_t)(((tc * 64 + kk16) * 64 + l) * 8 + e)] = f2bf(v);
}

// Fused QKV projection v14: BM=64, BN=96 (N-half), BK=64; 512 blocks
// (256 M x 2 N-half, nh=bid>>8 same-XCD) x 384 threads (6 waves = 2 M-tiles
// x 3 N-tiles, mfma_f32_32x32x16_bf16).  LDS 40 KB -> 2 blocks/CU (barrier
// overlap partner).  W traffic halves vs BM=32 (98 MB); LDS bytes/FLOP
// ~1.8x lower via the 32x32 shape.  v8 pipeline skeleton: async W
// global_load_lds issued one step ahead, X reg-staged fp32->bf16 (packed
// cvt) into XOR-swizzled rows, one __syncthreads per K-step.
__global__ __launch_bounds__(384) void proj_kernel(const float* __restrict__ X,
                                                   const unsigned short* __restrict__ Wp,
                                                   unsigned short* __restrict__ Qs,
                                                   unsigned short* __restrict__ Kp,
                                                   unsigned short* __restrict__ Vp) {
    __shared__ short Xs[2][4096];     // 2 x 8 KB bf16 (64 rows x 64 k, swizzled)
    __shared__ short Wsh[2][6144];    // 2 x 12 KB bf16 (12 x 1KB fragments)

    const int tid = threadIdx.x;
    const int w   = tid >> 6;       // 0..5
    const int l   = tid & 63;
    const int m   = w / 3;          // M-tile (32 rows)
    const int ntL = w % 3;          // N-tile (32 cols) within half
    const int bid = blockIdx.x;
    const int mtile = bid & 255;
    const int nh    = bid >> 8;     // N-half (bid, bid+256 share XCD)
    const int rowbase = mtile * 64;

    // --- X staging: 512 u-slots by 384 threads (u0 = tid; u1 = tid+384, tid<128)
    // u: row r = u>>3, kcol = (u&7)*8 floats; write 16 B swizzled.
    const int r0 = tid >> 3;
    const float* xsrc0 = X + (size_t)(rowbase + r0) * CN + (tid & 7) * 8;
    const int xdst0 = r0 * 128 + (((tid & 7) * 16) ^ ((r0 & 7) << 4));
    const int u1 = tid + 384;
    const int r1 = u1 >> 3;
    const float* xsrc1 = X + (size_t)(rowbase + r1) * CN + (u1 & 7) * 8;
    const int xdst1 = r1 * 128 + (((u1 & 7) * 16) ^ ((r1 & 7) << 4));
    const bool st2 = (tid < 128);

    // --- W staging: 12 chunks of 1 KB per step; wave w owns chunks 2w, 2w+1.
    // chunk c: tcL = c>>2, kkL = c&3; step advance = 2048 elems (4 kk16).
    const unsigned short* wsrc[2];
    int wdst[2];
    #pragma unroll
    for (int i = 0; i < 2; ++i) {
        const int c = 2 * w + i;
        const int tcL = c >> 2, kkL = c & 3;
        wsrc[i] = Wp + (size_t)((nh * 3 + tcL) * 64 + kkL) * 512 + l * 8;
        wdst[i] = c * 1024;   // wave-uniform byte base
    }

    // --- compute-side LDS byte offsets (per lane) ---
    // A (32x32x16): lane l: row m*32+(l&31), k j*16 + (l>>5)*8; swizzled rows.
    int aaddr[4], baddr[4];
    #pragma unroll
    for (int j = 0; j < 4; ++j) {
        aaddr[j] = (m * 32 + (l & 31)) * 128 +
                   ((j * 32 + (l >> 5) * 16) ^ ((l & 7) << 4));
        baddr[j] = (ntL * 4 + j) * 1024 + l * 16;
    }

    f32x16 acc = {0.f, 0.f, 0.f, 0.f, 0.f, 0.f, 0.f, 0.f,
                  0.f, 0.f, 0.f, 0.f, 0.f, 0.f, 0.f, 0.f};

    {   // prologue: stage step 0 into buffer 0
        gload_lds16(wsrc[0], (char*)Wsh[0] + wdst[0]);
        gload_lds16(wsrc[1], (char*)Wsh[0] + wdst[1]);
        float4 xa = *(const float4*)(xsrc0);
        float4 xb = *(const float4*)(xsrc0 + 4);
        int4 xc;
        xc.x = pk2(xa.x, xa.y); xc.y = pk2(xa.z, xa.w);
        xc.z = pk2(xb.x, xb.y); xc.w = pk2(xb.z, xb.w);
        *(int4*)((char*)Xs[0] + xdst0) = xc;
        if (st2) {
            float4 ya = *(const float4*)(xsrc1);
            float4 yb = *(const float4*)(xsrc1 + 4);
            int4 yc;
            yc.x = pk2(ya.x, ya.y); yc.y = pk2(ya.z, ya.w);
            yc.z = pk2(yb.x, yb.y); yc.w = pk2(yb.z, yb.w);
            *(int4*)((char*)Xs[0] + xdst1) = yc;
        }
        __syncthreads();
    }

    for (int s = 0; s < 16; ++s) {
        const int cur = s & 1;
        const int nxt = cur ^ 1;
        const bool more = (s + 1) < 16;
        // 1) issue next step's async W copies + X reg loads BEFORE compute
        float4 xa, xb, ya, yb;
        if (more) {
            gload_lds16(wsrc[0] + (s + 1) * 2048, (char*)Wsh[nxt] + wdst[0]);
            gload_lds16(wsrc[1] + (s + 1) * 2048, (char*)Wsh[nxt] + wdst[1]);
            xa = *(const float4*)(xsrc0 + (s + 1) * 64);
            xb = *(const float4*)(xsrc0 + (s + 1) * 64 + 4);
            if (st2) {
                ya = *(const float4*)(xsrc1 + (s + 1) * 64);
                yb = *(const float4*)(xsrc1 + (s + 1) * 64 + 4);
            }
        }
        // 2) compute current buffer: 4 x (A read + B read + MFMA 32x32x16)
        #pragma unroll
        for (int j = 0; j < 4; ++j) {
            bf16x8 a = *(const bf16x8*)((char*)Xs[cur] + aaddr[j]);
            bf16x8 b = *(const bf16x8*)((char*)Wsh[cur] + baddr[j]);
            acc = __builtin_amdgcn_mfma_f32_32x32x16_bf16(a, b, acc, 0, 0, 0);
        }
        // 3) convert + write next X buffer
        if (more) {
            int4 xc;
            xc.x = pk2(xa.x, xa.y); xc.y = pk2(xa.z, xa.w);
            xc.z = pk2(xb.x, xb.y); xc.w = pk2(xb.z, xb.w);
            *(int4*)((char*)Xs[nxt] + xdst0) = xc;
            if (st2) {
                int4 yc;
                yc.x = pk2(ya.x, ya.y); yc.y = pk2(ya.z, ya.w);
                yc.z = pk2(yb.x, yb.y); yc.w = pk2(yb.z, yb.w);
                *(int4*)((char*)Xs[nxt] + xdst1) = yc;
            }
        }
        // 4) one barrier per K-step (drains async W copies + X writes)
        __syncthreads();
    }

    // D layout (32x32, HW-verified): col = l&31, row = (reg&3)+8*(reg>>2)+4*(l>>5)
    const int col = nh * 96 + ntL * 32 + (l & 31);
    const int mtx = col >> 6;          // uniform per (nh, ntL): 0=Q, 1=K, 2=V
    const int h   = col & 63;
    #pragma unroll
    for (int r16 = 0; r16 < 16; ++r16) {
        const int row32 = (r16 & 3) + 8 * (r16 >> 2) + 4 * (l >> 5);
        const int g = rowbase + m * 32 + row32;   // global token row
        const unsigned short val = f2bf(acc[r16]);
        const int b = g >> 11, tloc = g & 2047;
        const int kt = tloc >> 5;
        if (mtx == 0) {
            Qs[(size_t)g * 64 + h] = val;
        } else if (mtx == 1) {
            // K fragment-packed (16x16 attn layout): frag fa*2+ks, lane lgk*16+lqk
            const int fa = (tloc >> 4) & 1, lqk = tloc & 15;
            const int ks = h >> 5, lgk = (h >> 3) & 3, e = h & 7;
            Kp[(size_t)(b * 64 + kt) * 2048 + (fa * 2 + ks) * 512 +
               (lgk * 16 + lqk) * 8 + e] = val;
        } else {
            // V fragment-packed: frag nf, lane lgv*16+lqv
            const int tt = tloc & 31;
            const int lgv = (tt & 15) >> 2;
            const int e = (tt < 16) ? (tt & 3) : 4 + (tt & 3);
            const int nf = h >> 4, lqv = h & 15;
            Vp[(size_t)(b * 64 + kt) * 2048 + nf * 512 +
               (lgv * 16 + lqv) * 8 + e] = val;
        }
    }
}

// Block-cooperative causal flash attention (round-8 proven, verbatim).
// Block = (qt, b): 1024 blocks x 4 waves; heavy q-tiles launch first.
__global__ __launch_bounds__(256) void attn_kernel(const unsigned short* __restrict__ Qs,
                                                   const unsigned short* __restrict__ Kp,
                                                   const unsigned short* __restrict__ Vp,
                                                   float* __restrict__ Out) {
    __shared__ float lm[4][16];
    __shared__ float ll[4][16];
    __shared__ float facc[4][1024];

    const int tid = threadIdx.x;
    const int w  = tid >> 6;
    const int l  = tid & 63;
    const int lq = l & 15;
    const int lg = l >> 4;
    const int bid = blockIdx.x;
    const int qt = 127 - (bid >> 3);   // heavy first
    const int b  = bid & 7;
    const int q0 = qt * 16;
    const int nt = (qt >> 1) + 1;

    const unsigned short* Qb = Qs + (size_t)b * TN * 64;
    const unsigned short* KVbase_k = Kp + (size_t)b * 64 * 2048 + (size_t)l * 8;
    const unsigned short* KVbase_v = Vp + (size_t)b * 64 * 2048 + (size_t)l * 8;

    const f32x4 zero4 = {0.f, 0.f, 0.f, 0.f};

    bf16x8 qa0 = *(const bf16x8*)(Qb + (size_t)(q0 + lq) * 64 + lg * 8);
    bf16x8 qa1 = *(const bf16x8*)(Qb + (size_t)(q0 + lq) * 64 + 32 + lg * 8);

    f32x4 acc[4] = {zero4, zero4, zero4, zero4};
    float mrow = -1e30f;
    float lrow = 0.f;

    bf16x8 Kc[4], Vc[4], Kn[4], Vn[4];
    int kt = w;
    if (kt < nt) {
        const size_t tb = (size_t)kt * 2048;
        #pragma unroll
        for (int i = 0; i < 4; ++i) {
            Kc[i] = *(const bf16x8*)(KVbase_k + tb + i * 512);
            Vc[i] = *(const bf16x8*)(KVbase_v + tb + i * 512);
        }
    }

    for (; kt < nt; kt += 4) {
        const int ktn = kt + 4;
        if (ktn < nt) {   // prefetch next tile (coalesced 1KB loads)
            const size_t tb = (size_t)ktn * 2048;
            #pragma unroll
            for (int i = 0; i < 4; ++i) {
                Kn[i] = *(const bf16x8*)(KVbase_k + tb + i * 512);
                Vn[i] = *(const bf16x8*)(KVbase_v + tb + i * 512);
            }
        }

        const int key0 = kt * 32;
        f32x4 s[2];
        s[0] = __builtin_amdgcn_mfma_f32_16x16x32_bf16(Kc[0], qa0, zero4, 0, 0, 0);
        s[0] = __builtin_amdgcn_mfma_f32_16x16x32_bf16(Kc[1], qa1, s[0], 0, 0, 0);
        s[1] = __builtin_amdgcn_mfma_f32_16x16x32_bf16(Kc[2], qa0, zero4, 0, 0, 0);
        s[1] = __builtin_amdgcn_mfma_f32_16x16x32_bf16(Kc[3], qa1, s[1], 0, 0, 0);

        if (kt == nt - 1) {   // only the diagonal tile needs masking
            const int q = q0 + lq;
            #pragma unroll
            for (int fa = 0; fa < 2; ++fa)
                #pragma unroll
                for (int r = 0; r < 4; ++r) {
                    const int key = key0 + fa * 16 + 4 * lg + r;
                    if (key > q) s[fa][r] = -1e30f;
                }
        }

        float m1 = fmaxf(fmaxf(s[0][0], s[0][1]), s[0][2]);
        float m2 = fmaxf(fmaxf(s[0][3], s[1][0]), s[1][1]);
        float m3 = fmaxf(fmaxf(s[1][2], s[1][3]), m1);
        float tm = fmaxf(m2, m3);
        tm = fmaxf(tm, __shfl_xor(tm, 16));
        tm = fmaxf(tm, __shfl_xor(tm, 32));

        // defer-max: only rescale when max grows by > 8 (P bounded by 2^8)
        if (!__all(tm <= mrow + 8.0f)) {
            const float mnew = fmaxf(mrow, tm);
            const float cc = __builtin_amdgcn_exp2f(mrow - mnew);
            lrow *= cc;
            float cb[4];
            #pragma unroll
            for (int i = 0; i < 4; ++i) cb[i] = __shfl(cc, 4 * lg + i);
            #pragma unroll
            for (int nf = 0; nf < 4; ++nf)
                #pragma unroll
                for (int i = 0; i < 4; ++i) acc[nf][i] *= cb[i];
            mrow = mnew;
        }

        float p[2][4];
        float psum = 0.f;
        #pragma unroll
        for (int fa = 0; fa < 2; ++fa)
            #pragma unroll
            for (int r = 0; r < 4; ++r) {
                p[fa][r] = __builtin_amdgcn_exp2f(s[fa][r] - mrow);
                psum += p[fa][r];
            }
        psum += __shfl_xor(psum, 16);
        psum += __shfl_xor(psum, 32);
        lrow += psum;

        bf16x8 pa;
        pa[0] = (short)f2bf(p[0][0]); pa[1] = (short)f2bf(p[0][1]);
        pa[2] = (short)f2bf(p[0][2]); pa[3] = (short)f2bf(p[0][3]);
        pa[4] = (short)f2bf(p[1][0]); pa[5] = (short)f2bf(p[1][1]);
        pa[6] = (short)f2bf(p[1][2]); pa[7] = (short)f2bf(p[1][3]);

        acc[0] = __builtin_amdgcn_mfma_f32_16x16x32_bf16(pa, Vc[0], acc[0], 0, 0, 0);
        acc[1] = __builtin_amdgcn_mfma_f32_16x16x32_bf16(pa, Vc[1], acc[1], 0, 0, 0);
        acc[2] = __builtin_amdgcn_mfma_f32_16x16x32_bf16(pa, Vc[2], acc[2], 0, 0, 0);
        acc[3] = __builtin_amdgcn_mfma_f32_16x16x32_bf16(pa, Vc[3], acc[3], 0, 0, 0);

        #pragma unroll
        for (int i = 0; i < 4; ++i) { Kc[i] = Kn[i]; Vc[i] = Vn[i]; }
    }

    // store partial state to LDS
    if (lg == 0) {
        lm[w][lq] = mrow;
        ll[w][lq] = lrow;
    }
    #pragma unroll
    for (int nf = 0; nf < 4; ++nf)
        #pragma unroll
        for (int i = 0; i < 4; ++i)
            facc[w][(4 * lg + i) * 64 + nf * 16 + lq] = acc[nf][i];

    __syncthreads();

    // merge 4 wave-partials and write Out
    #pragma unroll
    for (int ii = 0; ii < 4; ++ii) {
        const int e = tid + ii * 256;
        const int q = e >> 6;
        const int h = e & 63;
        const float M = fmaxf(fmaxf(lm[0][q], lm[1][q]),
                              fmaxf(lm[2][q], lm[3][q]));
        float L = 0.f, O = 0.f;
        #pragma unroll
        for (int c = 0; c < 4; ++c) {
            const float wgt = __builtin_amdgcn_exp2f(lm[c][q] - M);
            L += wgt * ll[c][q];
            O += wgt * facc[c][q * 64 + h];
        }
        Out[((size_t)b * TN + q0 + q) * 64 + h] = O / L;
    }
}

extern "C" void kernel_launch(void* const* d_in, const int* in_sizes, int n_in,
                              void* d_out, int out_size, void* d_ws, size_t ws_size,
                              hipStream_t stream) {
    const float* X  = (const float*)d_in[0];
    const float* Wq = (const float*)d_in[1];
    const float* Wk = (const float*)d_in[2];
    const float* Wv = (const float*)d_in[3];
    float* Out = (float*)d_out;

    char* ws = (char*)d_ws;
    unsigned short* Wp = (unsigned short*)(ws);                 // 384 KB (pad 512 KB)
    unsigned short* Qs = (unsigned short*)(ws + (512u << 10));  // 2 MB
    unsigned short* Kp = Qs + (size_t)16384 * 64;               // 2 MB
    unsigned short* Vp = Kp + (size_t)16384 * 64;               // 2 MB

    hipLaunchKernelGGL(wconv_kernel, dim3(768), dim3(256), 0, stream, Wq, Wk, Wv, Wp);
    hipLaunchKernelGGL(proj_kernel,  dim3(512), dim3(384), 0, stream, X, Wp, Qs, Kp, Vp);
    hipLaunchKernelGGL(attn_kernel,  dim3(1024), dim3(256), 0, stream, Qs, Kp, Vp, Out);
}